// Round 8
// baseline (648.144 us; speedup 1.0000x reference)
//
#include <hip/hip_runtime.h>
#include <hip/hip_fp16.h>
#include <math.h>

#define NN 100000
#define NE 3200000
#define CF 512

#define NPARTS  8
#define PART    12500              // nodes per partition (50 KB LDS hist)
#define NSLICES 64                 // edge slices
#define EPB     (NE / NSLICES)     // 50000 edges per block
#define NPB     (NSLICES * NPARTS) // 512 blocks -> 2 blocks/CU
#define NODES_PER_BLK 196          // GEMV: 512*196 >= NN

// ---- ws layout (bytes) ----
// dpart : u16 [NPB][PART]  @ 0           (12,800,000)
// spart : half [NPB][PART] @ 12,800,000  (12,800,000)
// g     : f32[NN]          @ 25,600,000
// h     : f32[NN]          @ 26,000,000
// dinv  : f32[NN]          @ 26,400,000
// ctr   : u32[8]           @ 26,800,000
#define OFF_SPART 12800000
#define OFF_G     25600000
#define OFF_H     26000000
#define OFF_DINV  26400000
#define OFF_CTR   26800000

// Per-wave int64-layout self-detect (high words of int64 edge values are 0).
__device__ __forceinline__ bool detect_f64(const int* e32) {
    unsigned v = ((const unsigned*)e32)[2 * (threadIdx.x & 63) + 1];
    return __ballot(v != 0u) == 0ULL;
}

__device__ __forceinline__ int4 load_col4(const int* e32, bool f64, int e) {
    if (f64) {
        const int4* q = (const int4*)(e32 + 2 * (NE + e));
        int4 a = q[0], b = q[1];
        return make_int4(a.x, a.z, b.x, b.z);
    }
    return *(const int4*)(e32 + NE + e);
}
__device__ __forceinline__ int load_row(const int* e32, bool f64, int e) {
    return f64 ? e32[2 * e] : e32[e];
}

// ---------------------------------------------------------------------------
// K1 (R1-proven verbatim + ctr zeroing): waves 0-11 deg histogram over the
// block's edge slice; waves 12-15 GEMV h = x @ W^T for 196 nodes.
// Sibling blocks of a slice are congruent mod 8 -> same XCD L2 for col stream.
// ---------------------------------------------------------------------------
__global__ __launch_bounds__(1024) void deg_h_kernel(const int* __restrict__ e32,
                                                     const float* __restrict__ x,
                                                     const float* __restrict__ W,
                                                     unsigned short* __restrict__ deg_part,
                                                     float* __restrict__ h,
                                                     unsigned* __restrict__ ctr) {
    __shared__ int hist[PART];
    int tid = threadIdx.x;
    if (blockIdx.x == 0 && tid < 8) ctr[tid] = 0u;   // zero K3's tickets (ws poisoned)
    for (int i = tid; i < PART; i += 1024) hist[i] = 0;
    __syncthreads();
    int w = tid >> 6, lane = tid & 63;
    if (w < 12) {
        bool f64 = detect_f64(e32);
        int p = blockIdx.x >> 6;
        int s = blockIdx.x & 63;
        int lo = p * PART;
        int base = s * EPB;
        for (int e = base + tid * 4; e < base + EPB; e += 3072) {
            int4 c = load_col4(e32, f64, e);
            unsigned l0 = (unsigned)(c.x - lo), l1 = (unsigned)(c.y - lo);
            unsigned l2 = (unsigned)(c.z - lo), l3 = (unsigned)(c.w - lo);
            if (l0 < PART) atomicAdd(&hist[l0], 1);
            if (l1 < PART) atomicAdd(&hist[l1], 1);
            if (l2 < PART) atomicAdd(&hist[l2], 1);
            if (l3 < PART) atomicAdd(&hist[l3], 1);
        }
    } else {
        const float4* Wr = (const float4*)W;
        float4 w0 = Wr[lane], w1 = Wr[lane + 64];   // W invariant, in regs
        int start = blockIdx.x * NODES_PER_BLK;
        int end = start + NODES_PER_BLK;
        for (int i = start + (w - 12) * 2; i < end; i += 8) {
            int i1 = i + 1;
            float s0 = 0.f, s1 = 0.f;
            if (i < NN) {
                const float4* xr = (const float4*)(x + (size_t)i * CF);
                float4 a = xr[lane], bq = xr[lane + 64];
                s0 = a.x * w0.x + a.y * w0.y + a.z * w0.z + a.w * w0.w
                   + bq.x * w1.x + bq.y * w1.y + bq.z * w1.z + bq.w * w1.w;
            }
            if (i1 < NN) {
                const float4* xr = (const float4*)(x + (size_t)i1 * CF);
                float4 a = xr[lane], bq = xr[lane + 64];
                s1 = a.x * w0.x + a.y * w0.y + a.z * w0.z + a.w * w0.w
                   + bq.x * w1.x + bq.y * w1.y + bq.z * w1.z + bq.w * w1.w;
            }
#pragma unroll
            for (int off = 32; off >= 1; off >>= 1) {
                s0 += __shfl_down(s0, off, 64);
                s1 += __shfl_down(s1, off, 64);
            }
            if (lane == 0) {
                if (i < NN) h[i] = s0;
                if (i1 < NN) h[i1] = s1;
            }
        }
    }
    __syncthreads();
    unsigned short* outp = deg_part + (size_t)blockIdx.x * PART;
    for (int i = tid; i < PART; i += 1024) outp[i] = (unsigned short)hist[i];
}

// K2 (R1-proven verbatim): dinv = rsqrt(1 + sum deg partials); g = h * dinv
__global__ void dinv_g_kernel(const unsigned short* __restrict__ deg_part,
                              const float* __restrict__ h,
                              float* __restrict__ dinv,
                              float* __restrict__ g) {
    int i = blockIdx.x * blockDim.x + threadIdx.x;
    if (i >= NN) return;
    int p = i / PART, l = i - p * PART;
    const unsigned short* bp = deg_part + ((size_t)(p << 6)) * PART + l;
    int d = 1;
#pragma unroll
    for (int s = 0; s < NSLICES; ++s) d += bp[(size_t)s * PART];
    float di = rsqrtf((float)d);
    dinv[i] = di;
    g[i] = h[i] * di;
}

// ---------------------------------------------------------------------------
// K3: scatter s[col] += g[row] -- R1-proven CONDITIONAL form (masked row-load
// + masked gather: ~3.2M total gather transactions, not 25.6M) + fused final:
// the LAST block of each partition (ctr[p]==63) reduces the 64 half partials
// + g + dinv -> sigmoid -> out for its 12500 nodes.
// ---------------------------------------------------------------------------
__global__ __launch_bounds__(1024) void scatter_final(const int* __restrict__ e32,
                                                      const float* __restrict__ g,
                                                      const float* __restrict__ dinv,
                                                      const float* __restrict__ b,
                                                      __half* __restrict__ spart,
                                                      unsigned* __restrict__ ctr,
                                                      float* __restrict__ out) {
    __shared__ float hs[PART];
    __shared__ int lastflag;
    int tid = threadIdx.x;
    for (int i = tid; i < PART; i += 1024) hs[i] = 0.f;
    __syncthreads();

    bool f64 = detect_f64(e32);
    int p = blockIdx.x >> 6;          // 0..7
    int s = blockIdx.x & 63;          // 0..63
    int lo = p * PART;
    int base = s * EPB;
    for (int e = base + tid * 4; e < base + EPB; e += 4096) {
        int4 c = load_col4(e32, f64, e);
        unsigned l0 = (unsigned)(c.x - lo), l1 = (unsigned)(c.y - lo);
        unsigned l2 = (unsigned)(c.z - lo), l3 = (unsigned)(c.w - lo);
        if (l0 < PART) atomicAdd(&hs[l0], g[load_row(e32, f64, e + 0)]);
        if (l1 < PART) atomicAdd(&hs[l1], g[load_row(e32, f64, e + 1)]);
        if (l2 < PART) atomicAdd(&hs[l2], g[load_row(e32, f64, e + 2)]);
        if (l3 < PART) atomicAdd(&hs[l3], g[load_row(e32, f64, e + 3)]);
    }
    __syncthreads();
    {
        __half* outp = spart + (size_t)blockIdx.x * PART;
        for (int i = tid; i < PART; i += 1024) outp[i] = __float2half(hs[i]);
    }

    // ---- last-block-per-partition fused final ----
    __threadfence();                  // release our partial writes
    __syncthreads();
    if (tid == 0) {
        unsigned old = atomicAdd(&ctr[p], 1u);
        lastflag = (old == (unsigned)(NSLICES - 1)) ? 1 : 0;
    }
    __syncthreads();
    if (!lastflag) return;
    __threadfence();                  // acquire: see all partitions' partials

    const __half* bp = spart + (size_t)(p * NSLICES) * PART;
    float bias = b[0];
    for (int l = tid; l < PART; l += 1024) {
        float acc = 0.f;
#pragma unroll 8
        for (int s2 = 0; s2 < NSLICES; ++s2) acc += __half2float(bp[(size_t)s2 * PART + l]);
        int i = lo + l;
        float v = dinv[i] * (acc + g[i]) + bias;
        out[i] = 1.f / (1.f + expf(-v));
    }
}

extern "C" void kernel_launch(void* const* d_in, const int* in_sizes, int n_in,
                              void* d_out, int out_size, void* d_ws, size_t ws_size,
                              hipStream_t stream) {
    const float* x = (const float*)d_in[0];
    const int* eidx = (const int*)d_in[1];
    const float* W = (const float*)d_in[2];
    const float* b = (const float*)d_in[3];
    float* out = (float*)d_out;

    char* ws = (char*)d_ws;
    unsigned short* dpart = (unsigned short*)(ws);
    __half* spart = (__half*)(ws + OFF_SPART);
    float* g = (float*)(ws + OFF_G);
    float* h = (float*)(ws + OFF_H);
    float* dinv = (float*)(ws + OFF_DINV);
    unsigned* ctr = (unsigned*)(ws + OFF_CTR);

    deg_h_kernel<<<NPB, 1024, 0, stream>>>(eidx, x, W, dpart, h, ctr);
    dinv_g_kernel<<<(NN + 255) / 256, 256, 0, stream>>>(dpart, h, dinv, g);
    scatter_final<<<NPB, 1024, 0, stream>>>(eidx, g, dinv, b, spart, ctr, out);
}

// Round 9
// 362.267 us; speedup vs baseline: 1.7891x; 1.7891x over previous
//
#include <hip/hip_runtime.h>
#include <hip/hip_fp16.h>
#include <math.h>

#define NN 100000
#define NE 3200000
#define CF 512

// ---- deg pass geometry: NP=4 partitions, packed u16 counters (50 KB LDS) ----
#define DNP     4
#define DPT     25000              // nodes per deg partition
#define DNSL    128                // deg edge slices
#define DEPB    (NE / DNSL)        // 25000 edges per deg block
#define NPB     512                // DNP*DNSL = 512 = NPARTS*NSLICES (scatter)
#define NODES_PER_BLK 196          // GEMV: 512*196 >= NN

// ---- scatter pass geometry (R1-proven verbatim) ----
#define NPARTS  8
#define PART    12500              // 50 KB f32 LDS hist
#define NSLICES 64
#define EPB     (NE / NSLICES)     // 50000 edges per scatter block

// ---- ws layout (bytes) ----
// dpart : u16 [512][DPT]   @ 0           (25,600,000)
// spart : half [512][PART] @ 25,600,000  (12,800,000)
// g     : f32[NN]          @ 38,400,000
// h     : f32[NN]          @ 38,800,000
// dinv  : f32[NN]          @ 39,200,000
#define OFF_SPART 25600000
#define OFF_G     38400000
#define OFF_H     38800000
#define OFF_DINV  39200000

// Per-wave int64-layout self-detect (high words of int64 edge values are 0).
__device__ __forceinline__ bool detect_f64(const int* e32) {
    unsigned v = ((const unsigned*)e32)[2 * (threadIdx.x & 63) + 1];
    return __ballot(v != 0u) == 0ULL;
}

__device__ __forceinline__ int4 load_col4(const int* e32, bool f64, int e) {
    if (f64) {
        const int4* q = (const int4*)(e32 + 2 * (NE + e));
        int4 a = q[0], b = q[1];
        return make_int4(a.x, a.z, b.x, b.z);
    }
    return *(const int4*)(e32 + NE + e);
}
__device__ __forceinline__ int load_row(const int* e32, bool f64, int e) {
    return f64 ? e32[2 * e] : e32[e];
}

// ---------------------------------------------------------------------------
// K1: waves 0-11 deg histogram (NP=4, packed u16 pairs in u32: no carry risk,
// max deg << 65535 -- R5-proven scheme); waves 12-15 GEMV h = x @ W^T.
// 512 blocks, 50 KB static LDS -> 2 blocks/CU (R1 occupancy preserved).
// Partition-siblings of a slice differ by 128 in blockIdx == 0 mod 8 -> same
// XCD L2 for the shared col stream.
// ---------------------------------------------------------------------------
__global__ __launch_bounds__(1024) void deg_h_kernel(const int* __restrict__ e32,
                                                     const float* __restrict__ x,
                                                     const float* __restrict__ W,
                                                     unsigned short* __restrict__ deg_part,
                                                     float* __restrict__ h) {
    __shared__ unsigned hist[DPT / 2];          // 12500 u32 = 25000 packed u16
    int tid = threadIdx.x;
    for (int i = tid; i < DPT / 2; i += 1024) hist[i] = 0u;
    __syncthreads();
    int w = tid >> 6, lane = tid & 63;
    if (w < 12) {
        bool f64 = detect_f64(e32);
        int p = blockIdx.x >> 7;                // 0..3
        int s = blockIdx.x & 127;               // 0..127
        unsigned lo = (unsigned)(p * DPT);
        int base = s * DEPB;
        for (int e = base + tid * 4; e < base + DEPB; e += 3072) {
            int4 c = load_col4(e32, f64, e);
            unsigned l0 = (unsigned)c.x - lo, l1 = (unsigned)c.y - lo;
            unsigned l2 = (unsigned)c.z - lo, l3 = (unsigned)c.w - lo;
            if (l0 < DPT) atomicAdd(&hist[l0 >> 1], 1u << ((l0 & 1) << 4));
            if (l1 < DPT) atomicAdd(&hist[l1 >> 1], 1u << ((l1 & 1) << 4));
            if (l2 < DPT) atomicAdd(&hist[l2 >> 1], 1u << ((l2 & 1) << 4));
            if (l3 < DPT) atomicAdd(&hist[l3 >> 1], 1u << ((l3 & 1) << 4));
        }
    } else {
        const float4* Wr = (const float4*)W;
        float4 w0 = Wr[lane], w1 = Wr[lane + 64];   // W invariant, in regs
        int start = blockIdx.x * NODES_PER_BLK;
        int end = start + NODES_PER_BLK;
        for (int i = start + (w - 12) * 2; i < end; i += 8) {
            int i1 = i + 1;
            float s0 = 0.f, s1 = 0.f;
            if (i < NN) {
                const float4* xr = (const float4*)(x + (size_t)i * CF);
                float4 a = xr[lane], bq = xr[lane + 64];
                s0 = a.x * w0.x + a.y * w0.y + a.z * w0.z + a.w * w0.w
                   + bq.x * w1.x + bq.y * w1.y + bq.z * w1.z + bq.w * w1.w;
            }
            if (i1 < NN) {
                const float4* xr = (const float4*)(x + (size_t)i1 * CF);
                float4 a = xr[lane], bq = xr[lane + 64];
                s1 = a.x * w0.x + a.y * w0.y + a.z * w0.z + a.w * w0.w
                   + bq.x * w1.x + bq.y * w1.y + bq.z * w1.z + bq.w * w1.w;
            }
#pragma unroll
            for (int off = 32; off >= 1; off >>= 1) {
                s0 += __shfl_down(s0, off, 64);
                s1 += __shfl_down(s1, off, 64);
            }
            if (lane == 0) {
                if (i < NN) h[i] = s0;
                if (i1 < NN) h[i1] = s1;
            }
        }
    }
    __syncthreads();
    unsigned short* outp = deg_part + (size_t)blockIdx.x * DPT;
    for (int i = tid; i < DPT; i += 1024)
        outp[i] = (unsigned short)((hist[i >> 1] >> ((i & 1) << 4)) & 0xffffu);
}

// K2: dinv = rsqrt(1 + sum_{128 slices} deg partials); g = h * dinv
__global__ void dinv_g_kernel(const unsigned short* __restrict__ deg_part,
                              const float* __restrict__ h,
                              float* __restrict__ dinv,
                              float* __restrict__ g) {
    int i = blockIdx.x * blockDim.x + threadIdx.x;
    if (i >= NN) return;
    int p = i / DPT, l = i - p * DPT;
    const unsigned short* bp = deg_part + ((size_t)p * DNSL) * DPT + l;
    unsigned d = 1;
#pragma unroll 16
    for (int s = 0; s < DNSL; ++s) d += bp[(size_t)s * DPT];
    float di = rsqrtf((float)d);
    dinv[i] = di;
    g[i] = h[i] * di;
}

// K3 (R1-proven verbatim): scatter s[col] += g[row], conditional masked
// gathers (~3.2M total gather transactions), LDS-privatized, half partials.
// NO fences, NO tickets (R8 lesson: device-scope fences cost ~285 us).
__global__ __launch_bounds__(1024) void scatter_lds_kernel(const int* __restrict__ e32,
                                                           const float* __restrict__ g,
                                                           __half* __restrict__ s_part) {
    __shared__ float hs[PART];
    int tid = threadIdx.x;
    for (int i = tid; i < PART; i += 1024) hs[i] = 0.f;
    __syncthreads();
    bool f64 = detect_f64(e32);
    int p = blockIdx.x >> 6;
    int s = blockIdx.x & 63;
    int lo = p * PART;
    int base = s * EPB;
    for (int e = base + tid * 4; e < base + EPB; e += 4096) {
        int4 c = load_col4(e32, f64, e);
        unsigned l0 = (unsigned)(c.x - lo), l1 = (unsigned)(c.y - lo);
        unsigned l2 = (unsigned)(c.z - lo), l3 = (unsigned)(c.w - lo);
        if (l0 < PART) atomicAdd(&hs[l0], g[load_row(e32, f64, e + 0)]);
        if (l1 < PART) atomicAdd(&hs[l1], g[load_row(e32, f64, e + 1)]);
        if (l2 < PART) atomicAdd(&hs[l2], g[load_row(e32, f64, e + 2)]);
        if (l3 < PART) atomicAdd(&hs[l3], g[load_row(e32, f64, e + 3)]);
    }
    __syncthreads();
    __half* outp = s_part + (size_t)blockIdx.x * PART;
    for (int i = tid; i < PART; i += 1024) outp[i] = __float2half(hs[i]);
}

// K4 (R1-proven verbatim): out = sigmoid(dinv * (sum partials + g) + b)
__global__ void final_kernel(const __half* __restrict__ s_part,
                             const float* __restrict__ g,
                             const float* __restrict__ dinv,
                             const float* __restrict__ b,
                             float* __restrict__ out) {
    int i = blockIdx.x * blockDim.x + threadIdx.x;
    if (i >= NN) return;
    int p = i / PART, l = i - p * PART;
    const __half* bp = s_part + ((size_t)(p << 6)) * PART + l;
    float acc = g[i];
#pragma unroll
    for (int s = 0; s < NSLICES; ++s) acc += __half2float(bp[(size_t)s * PART]);
    float v = dinv[i] * acc + b[0];
    out[i] = 1.f / (1.f + expf(-v));
}

extern "C" void kernel_launch(void* const* d_in, const int* in_sizes, int n_in,
                              void* d_out, int out_size, void* d_ws, size_t ws_size,
                              hipStream_t stream) {
    const float* x = (const float*)d_in[0];
    const int* eidx = (const int*)d_in[1];
    const float* W = (const float*)d_in[2];
    const float* b = (const float*)d_in[3];
    float* out = (float*)d_out;

    char* ws = (char*)d_ws;
    unsigned short* dpart = (unsigned short*)(ws);
    __half* spart = (__half*)(ws + OFF_SPART);
    float* g = (float*)(ws + OFF_G);
    float* h = (float*)(ws + OFF_H);
    float* dinv = (float*)(ws + OFF_DINV);

    deg_h_kernel<<<NPB, 1024, 0, stream>>>(eidx, x, W, dpart, h);
    dinv_g_kernel<<<(NN + 255) / 256, 256, 0, stream>>>(dpart, h, dinv, g);
    scatter_lds_kernel<<<NPB, 1024, 0, stream>>>(eidx, g, spart);
    final_kernel<<<(NN + 255) / 256, 256, 0, stream>>>(spart, g, dinv, b, out);
}